// Round 6
// baseline (16.570 us; speedup 1.0000x reference)
//
#include <hip/hip_runtime.h>

// LengthRegulator fused single-kernel:
// reps = floor(dur + 0.5); out[b, m, :] = inputs[b, t, :] where
// cumsum[b][t] <= m < cumsum[b][t+1]; zeros for m >= output_lens[b].
// d_out = out flat [B*max_len*D] ++ output_lens [B] (as float).
//
// Block = one batch x 48 contiguous output frames, 384 threads (6 waves).
// Waves 0-3 redundantly shfl-scan the 512 durations (registers, 2 barriers)
// and scatter token ids into a 48-entry LDS frame->token map. Gather phase:
// each thread owns a fixed (frame_offset, d4) pair -> 12 independent,
// branch-free iterations (loads unconditional via clamp+select) so the
// compiler can keep all 12 global loads in flight; nt-stores stream out.

#define BATCH 16
#define T_IN 512
#define DIM 384
#define D4 96            // float4 per row
#define FPB 48           // output frames per block
#define NT 384           // threads per block (6 waves)
#define ITERS (FPB * D4 / NT)  // 12

typedef float floatx4 __attribute__((ext_vector_type(4)));

__global__ __launch_bounds__(NT) void lr_fused_kernel(
    const float* __restrict__ dur,
    const floatx4* __restrict__ in4,
    floatx4* __restrict__ out4,
    float* __restrict__ lens_out,
    int max_len, int gx) {
    __shared__ int wsum[4];
    __shared__ int smap[FPB];

    // XCD-chunked swizzle: give XCD k the contiguous range [k*nwg/8, ...).
    const int nwg = gridDim.x;               // 16 * gx, divisible by 8
    const int id = blockIdx.x;
    const int wid = (id & 7) * (nwg >> 3) + (id >> 3);
    const int b = wid / gx;                  // batch
    const int fx = wid - b * gx;             // frame-chunk within batch

    const int tid = threadIdx.x;
    const int lane = tid & 63;
    const int w = tid >> 6;
    const int f0 = fx * FPB;

    if (tid < FPB) smap[tid] = -1;           // default: zero-fill frame

    // ---- scan: waves 0-3 hold 2 reps each, registers only ----
    int r0 = 0, s = 0, incl = 0;
    if (tid < 256) {
        float2 dp = *(const float2*)(dur + b * T_IN + 2 * tid);
        r0 = (int)floorf(dp.x + 0.5f);
        int r1 = (int)floorf(dp.y + 0.5f);
        s = r0 + r1;
        incl = s;
        #pragma unroll
        for (int off = 1; off < 64; off <<= 1) {
            int v = __shfl_up(incl, off);
            if (lane >= off) incl += v;
        }
        if (lane == 63) wsum[w] = incl;
    }
    __syncthreads();

    if (tid < 256) {
        int waveoff = 0;
        #pragma unroll
        for (int i = 0; i < 4; ++i)
            if (i < w) waveoff += wsum[i];
        const int c0 = waveoff + incl - s;   // cumsum before token 2*tid
        const int c1 = c0 + r0;              // before token 2*tid+1
        const int c2 = c0 + s;               // before token 2*tid+2
        const int f1 = f0 + FPB;
        int lo = max(c0, f0), hi = min(c1, f1);
        for (int j = lo; j < hi; ++j) smap[j - f0] = 2 * tid;
        lo = max(c1, f0); hi = min(c2, f1);
        for (int j = lo; j < hi; ++j) smap[j - f0] = 2 * tid + 1;
        if (fx == 0 && tid == 255) lens_out[b] = (float)c2;
    }
    __syncthreads();

    // ---- gather: 48 frames = 4608 float4, 12 per thread, branch-free ----
    const int f_off = tid / D4;              // 0..3 (computed once)
    const int d4 = tid - f_off * D4;         // 0..95
    const int per_b = max_len * D4;
    const floatx4* src_b = in4 + (size_t)b * T_IN * D4;
    floatx4* dst_b = out4 + (size_t)b * per_b;

    #pragma unroll
    for (int k = 0; k < ITERS; ++k) {
        const int lf = k * 4 + f_off;        // local frame 0..47
        const int frame = f0 + lf;
        const int t = smap[lf];
        const int ts = t < 0 ? 0 : t;        // clamp: load unconditional
        floatx4 val = src_b[ts * D4 + d4];
        if (t < 0) val = (floatx4)(0.f);
        if (frame < max_len)
            __builtin_nontemporal_store(val, &dst_b[frame * D4 + d4]);
    }
}

extern "C" void kernel_launch(void* const* d_in, const int* in_sizes, int n_in,
                              void* d_out, int out_size, void* d_ws, size_t ws_size,
                              hipStream_t stream) {
    const float* inputs = (const float*)d_in[0];
    const float* durations = (const float*)d_in[1];
    float* out = (float*)d_out;

    const int max_len = (out_size - BATCH) / (BATCH * DIM);
    float* lens_out = out + (size_t)BATCH * max_len * DIM;

    const int gx = (max_len + FPB - 1) / FPB;
    dim3 grid(gx * BATCH);
    lr_fused_kernel<<<grid, NT, 0, stream>>>(durations, (const floatx4*)inputs,
                                             (floatx4*)out, lens_out, max_len,
                                             gx);
}